// Round 1
// baseline (167.724 us; speedup 1.0000x reference)
//
#include <hip/hip_runtime.h>

// KAN conv: x(8,32,32,64) fp32, cp(64,64,3,3,16), w1/w2(64,64,3,3) -> out(8,32,32,64)
// out[b,p,q,f] = sum_{ij,c} [ lerp(w1*cp over g at idx(v), frac(v)) + silu(v)*w2 ],
// v = x[b, p+di-1, q+dj-1, c] (zero-padded SAME).

#define NWCP 589824   // 9*64*16*64
#define NW2T 36864    // 9*64*64

// wcpT[((ij*64 + c)*16 + g)*64 + f] = w1[f,c,ij] * cp[f,c,ij,g]
__global__ __launch_bounds__(256) void prep_wcp(const float* __restrict__ cp,
                                                const float* __restrict__ w1,
                                                float* __restrict__ wcpT) {
    int tid = blockIdx.x * 256 + threadIdx.x;      // linear cp order: f*9216 + c*144 + ij*16 + g
    int f  = tid / 9216;
    int r  = tid - f * 9216;
    int c  = r / 144;
    int r2 = r - c * 144;
    int ij = r2 >> 4;
    int g  = r2 & 15;
    float v = w1[f * 576 + c * 9 + ij] * cp[tid];
    wcpT[((ij * 64 + c) * 16 + g) * 64 + f] = v;
}

// w2T[(ij*64 + c)*64 + f] = w2[f,c,ij]
__global__ __launch_bounds__(256) void prep_w2(const float* __restrict__ w2,
                                               float* __restrict__ w2T) {
    int tid = blockIdx.x * 256 + threadIdx.x;
    int f = tid & 63;
    int r = tid >> 6;
    int c = r & 63;
    int ij = r >> 6;
    w2T[tid] = w2[f * 576 + c * 9 + ij];
}

// One WG per (b,p,row-group): 256 rows * 3 ij-groups = 768 WGs of 256 threads.
// Wave wv (lanes = f) accumulates 8 pixels q = wv*8 + pp.
__global__ __launch_bounds__(256) void kan_main(const float* __restrict__ x,
                                                const float* __restrict__ wcpT,
                                                const float* __restrict__ w2T,
                                                float* __restrict__ out) {
    __shared__ float2 prm2[2048];   // (frac, silu) per (px,c)          16 KB
    __shared__ int    prmI[2048];   // idx*64 (dword offset of g-row)    8 KB
    __shared__ float  cps[4096];    // 4 c-slices of 16x64 cp            16 KB
    __shared__ float  w2s[256];     // 4 c-slices of w2 row              1 KB

    int bx    = blockIdx.x;
    int rowid = bx / 3;             // (b,p)
    int grp   = bx - rowid * 3;     // ij group: handles ij = grp*3 .. grp*3+2
    int b = rowid >> 5;
    int p = rowid & 31;

    int t    = threadIdx.x;
    int wv   = t >> 6;
    int lane = t & 63;

    float acc[8];
#pragma unroll
    for (int i = 0; i < 8; ++i) acc[i] = 0.f;

    for (int sij = 0; sij < 3; ++sij) {
        int ij = grp * 3 + sij;
        int di = ij / 3, dj = ij - di * 3;
        int row = p + di - 1;
        bool rowok = (row >= 0) && (row < 32);
        const float* xrow = x + ((b * 32 + row) * 32) * 64;

        __syncthreads();   // previous chunk compute done -> safe to overwrite prm
        // ---- param phase: spline idx/frac + silu for 32 px * 64 c, vectorized ----
#pragma unroll
        for (int rl = 0; rl < 8; ++rl) {
            int e  = t + rl * 256;
            int px = e >> 6;
            int c  = e & 63;
            int col = px + dj - 1;
            float v = 0.f;
            if (rowok && col >= 0 && col < 32) v = xrow[col * 64 + c];
            float xc = fminf(fmaxf(v, -1.f), 1.f);
            float tt = (xc + 1.f) * 7.5f;
            int idx = (int)tt;
            if (idx > 14) idx = 14;
            float frac = tt - (float)idx;
            float sv = v / (1.f + __expf(-v));
            prm2[e] = make_float2(frac, sv);
            prmI[e] = idx << 6;
        }

        // ---- pipelined c-chunks of 4 channels ----
        const float4* csrc = (const float4*)(wcpT + ij * 65536);  // 16*64*64 floats per ij
        const float4* wsrc = (const float4*)(w2T + ij * 4096);
        float4 cr0 = csrc[t];
        float4 cr1 = csrc[t + 256];
        float4 cr2 = csrc[t + 512];
        float4 cr3 = csrc[t + 768];
        float4 wr;
        if (t < 64) wr = wsrc[t];

        for (int chunk = 0; chunk < 16; ++chunk) {
            __syncthreads();   // prm ready / previous compute done
            ((float4*)cps)[t]       = cr0;
            ((float4*)cps)[t + 256] = cr1;
            ((float4*)cps)[t + 512] = cr2;
            ((float4*)cps)[t + 768] = cr3;
            if (t < 64) ((float4*)w2s)[t] = wr;
            __syncthreads();
            if (chunk < 15) {   // prefetch next chunk into registers (overlaps compute)
                const float4* n = csrc + (chunk + 1) * 1024;
                cr0 = n[t]; cr1 = n[t + 256]; cr2 = n[t + 512]; cr3 = n[t + 768];
                if (t < 64) wr = wsrc[(chunk + 1) * 64 + t];
            }
            int c0 = chunk * 4;
#pragma unroll
            for (int dc = 0; dc < 4; ++dc) {
                float w2v = w2s[dc * 64 + lane];
                int ebase = ((wv * 8) << 6) | (c0 + dc);
                int abase = dc * 1024 + lane;
#pragma unroll
                for (int pp = 0; pp < 8; ++pp) {
                    int e = ebase + (pp << 6);
                    float2 fs = prm2[e];               // broadcast (wave-uniform addr)
                    int a = abase + prmI[e];
                    float cp0 = cps[a];                // ds_read2_b32 pair, conflict-free
                    float cp1 = cps[a + 64];
                    float tmp = fmaf(fs.x, cp1 - cp0, cp0);
                    acc[pp] += tmp;
                    acc[pp] = fmaf(fs.y, w2v, acc[pp]);
                }
            }
        }
    }

    int pixbase = ((b * 32 + p) * 32 + wv * 8) * 64 + lane;
#pragma unroll
    for (int pp = 0; pp < 8; ++pp) {
        atomicAdd(&out[pixbase + pp * 64], acc[pp]);
    }
}

extern "C" void kernel_launch(void* const* d_in, const int* in_sizes, int n_in,
                              void* d_out, int out_size, void* d_ws, size_t ws_size,
                              hipStream_t stream) {
    const float* x  = (const float*)d_in[0];
    const float* cp = (const float*)d_in[1];
    const float* w1 = (const float*)d_in[2];
    const float* w2 = (const float*)d_in[3];
    float* outp = (float*)d_out;
    float* wcpT = (float*)d_ws;          // 589824 floats
    float* w2T  = wcpT + NWCP;           // 36864 floats  (ws needs ~2.4 MB)

    prep_wcp<<<NWCP / 256, 256, 0, stream>>>(cp, w1, wcpT);
    prep_w2<<<NW2T / 256, 256, 0, stream>>>(w2, w2T);
    hipMemsetAsync(d_out, 0, (size_t)out_size * sizeof(float), stream);
    kan_main<<<768, 256, 0, stream>>>(x, wcpT, w2T, outp);
}

// Round 2
// 117.759 us; speedup vs baseline: 1.4243x; 1.4243x over previous
//
#include <hip/hip_runtime.h>

// KAN conv as densified GEMM:
//   out[px,f] = sum_k Basis[px,k] * W[k,f],  px = (b,p,q) 8192, f = 64
//   k layout: 16 chunks (4 channels each) of 640 rows:
//     [0,576)   spline: (c_local*9+ij)*16 + g ; basis = (1-frac)@idx, frac@idx+1
//     [576,612) silu:    c_local*9+ij         ; basis = silu(v)
//     [612,640) zero pad (W rows = 0)
// W pre-swizzled into MFMA B-fragment order (16x16x32 f16).

typedef _Float16 v8h __attribute__((ext_vector_type(8)));
typedef float    v4f __attribute__((ext_vector_type(4)));

#define CHUNK_K 640
#define KPAD    10240            // 16 * 640
#define NSLOT   (KPAD * 64)      // f16 elements in swizzled W (1.31 MB)

// Wsw slot: ((ks*4 + nt)*64 + lane)*8 + j  holds W[k = ks*32 + (lane>>4)*8 + j][f = nt*16 + (lane&15)]
__global__ __launch_bounds__(256) void prep_wsw(const float* __restrict__ cp,
                                                const float* __restrict__ w1,
                                                const float* __restrict__ w2,
                                                _Float16* __restrict__ wsw) {
    int tid  = blockIdx.x * 256 + threadIdx.x;
    int j    = tid & 7;
    int lane = (tid >> 3) & 63;
    int rest = tid >> 9;
    int nt   = rest & 3;
    int ks   = rest >> 2;                    // 0..319
    int k    = ks * 32 + ((lane >> 4) << 3) + j;
    int f    = (nt << 4) + (lane & 15);
    int chunk = k / CHUNK_K;
    int kl    = k - chunk * CHUNK_K;
    float val = 0.f;
    if (kl < 576) {
        int c  = (chunk << 2) + kl / 144;
        int r  = kl % 144;
        int ij = r >> 4;
        int g  = r & 15;
        val = w1[f * 576 + c * 9 + ij] * cp[f * 9216 + c * 144 + ij * 16 + g];
    } else if (kl < 612) {
        int i2 = kl - 576;
        int c  = (chunk << 2) + i2 / 9;
        int ij = i2 % 9;
        val = w2[f * 576 + c * 9 + ij];
    }
    wsw[tid] = (_Float16)val;
}

// grid 512: blk = rowid*2 + kh. WG = 32 pixels (one (b,p) row), K-half kh.
// 4 waves split each chunk's 20 k-steps (5 each); full 32x64 acc per wave.
__global__ __launch_bounds__(256) void kan_mfma(const float* __restrict__ x,
                                                const _Float16* __restrict__ wsw,
                                                float* __restrict__ out) {
    __shared__ __align__(16) char smem[67584];
    float*    xs  = (float*)smem;                 // [3][32][68] f32, 26112 B (stride 68 breaks banks)
    _Float16* sb  = (_Float16*)(smem + 26112);    // [32][648] f16 basis, 41472 B (stride 648: 324 dw % 32 == 4)
    float*    red = (float*)(smem + 26112);       // [4][32][64] f32 reduction, aliases sb

    int blk   = blockIdx.x;
    int kh    = blk & 1;
    int rowid = blk >> 1;                         // (b,p)
    int b = rowid >> 5, p = rowid & 31;
    int t = threadIdx.x, wv = t >> 6, lane = t & 63;
    int m = lane & 15, kq = lane >> 4;

    // ---- stage x rows p-1..p+1 into LDS (zero-padded) ----
    for (int rr = 0; rr < 3; ++rr) {
        int pr = p + rr - 1;
        bool ok = (unsigned)pr < 32u;
        const v4f* src = (const v4f*)(x + ((b * 32 + pr) * 32) * 64);
        for (int i4 = t; i4 < 512; i4 += 256) {
            v4f v = ok ? src[i4] : (v4f){0.f, 0.f, 0.f, 0.f};
            int col = i4 >> 4, c4 = (i4 & 15) << 2;
            *(v4f*)(xs + (rr * 32 + col) * 68 + c4) = v;
        }
    }
    __syncthreads();

    v4f acc[2][4];
#pragma unroll
    for (int i = 0; i < 2; ++i)
#pragma unroll
        for (int n = 0; n < 4; ++n) acc[i][n] = (v4f){0.f, 0.f, 0.f, 0.f};

    for (int ch = 0; ch < 8; ++ch) {
        int gch = kh * 8 + ch;                    // global chunk 0..15
        // ---- zero basis (full 41472 B, vectorized) ----
        v4f z4 = (v4f){0.f, 0.f, 0.f, 0.f};
        for (int i4 = t; i4 < 2592; i4 += 256) ((v4f*)sb)[i4] = z4;
        __syncthreads();
        // ---- scatter: 32 px * 4 c * 9 ij = 1152 events ----
        int cbase = gch << 2;
        for (int it = 0; it < 5; ++it) {
            int e = t + it * 256;
            if (e < 1152) {
                int px = e / 36;
                int r  = e - px * 36;
                int cl = r / 9;
                int ij = r - cl * 9;
                int di = ij / 3;
                int dj = ij - di * 3;
                int col = px + dj - 1;
                float v = 0.f;
                if ((unsigned)col < 32u) v = xs[(di * 32 + col) * 68 + cbase + cl];
                float xc = fminf(fmaxf(v, -1.f), 1.f);
                float tt = (xc + 1.f) * 7.5f;
                int idx = (int)tt;
                if (idx > 14) idx = 14;
                float fr = tt - (float)idx;
                float sv = v * __builtin_amdgcn_rcpf(1.f + __expf(-v));
                _Float16* rowp = sb + px * 648 + cl * 144 + ij * 16;
                rowp[idx]     = (_Float16)(1.f - fr);
                rowp[idx + 1] = (_Float16)fr;
                sb[px * 648 + 576 + cl * 9 + ij] = (_Float16)sv;
            }
        }
        __syncthreads();
        // ---- MFMA: 20 k-steps, this wave takes 5 ----
        int gks = gch * 20 + wv * 5;
        const v8h* bp = (const v8h*)wsw + (size_t)gks * 256 + lane;
        const _Float16* ap0 = sb + m * 648 + (wv * 5) * 32 + kq * 8;
#pragma unroll
        for (int s = 0; s < 5; ++s) {
            v8h a0 = *(const v8h*)(ap0 + s * 32);
            v8h a1 = *(const v8h*)(ap0 + s * 32 + 16 * 648);
            v8h b0 = bp[s * 256];
            v8h b1 = bp[s * 256 + 64];
            v8h b2 = bp[s * 256 + 128];
            v8h b3 = bp[s * 256 + 192];
            acc[0][0] = __builtin_amdgcn_mfma_f32_16x16x32_f16(a0, b0, acc[0][0], 0, 0, 0);
            acc[0][1] = __builtin_amdgcn_mfma_f32_16x16x32_f16(a0, b1, acc[0][1], 0, 0, 0);
            acc[0][2] = __builtin_amdgcn_mfma_f32_16x16x32_f16(a0, b2, acc[0][2], 0, 0, 0);
            acc[0][3] = __builtin_amdgcn_mfma_f32_16x16x32_f16(a0, b3, acc[0][3], 0, 0, 0);
            acc[1][0] = __builtin_amdgcn_mfma_f32_16x16x32_f16(a1, b0, acc[1][0], 0, 0, 0);
            acc[1][1] = __builtin_amdgcn_mfma_f32_16x16x32_f16(a1, b1, acc[1][1], 0, 0, 0);
            acc[1][2] = __builtin_amdgcn_mfma_f32_16x16x32_f16(a1, b2, acc[1][2], 0, 0, 0);
            acc[1][3] = __builtin_amdgcn_mfma_f32_16x16x32_f16(a1, b3, acc[1][3], 0, 0, 0);
        }
        __syncthreads();
    }

    // ---- 4-wave reduction via LDS, then atomicAdd (2 K-half WGs combine) ----
#pragma unroll
    for (int mt = 0; mt < 2; ++mt)
#pragma unroll
        for (int nt = 0; nt < 4; ++nt)
#pragma unroll
            for (int r = 0; r < 4; ++r) {
                int px = mt * 16 + kq * 4 + r;     // C/D: row=(lane>>4)*4+reg
                int f  = nt * 16 + m;              //      col=lane&15
                red[wv * 2048 + px * 64 + f] = acc[mt][nt][r];
            }
    __syncthreads();
    v4f o0 = (v4f){0.f, 0.f, 0.f, 0.f}, o1 = o0;
    const v4f* r4 = (const v4f*)red;
#pragma unroll
    for (int w = 0; w < 4; ++w) {
        o0 += r4[w * 512 + t * 2];
        o1 += r4[w * 512 + t * 2 + 1];
    }
    float* op = out + rowid * 2048 + t * 8;
    atomicAdd(op + 0, o0.x); atomicAdd(op + 1, o0.y);
    atomicAdd(op + 2, o0.z); atomicAdd(op + 3, o0.w);
    atomicAdd(op + 4, o1.x); atomicAdd(op + 5, o1.y);
    atomicAdd(op + 6, o1.z); atomicAdd(op + 7, o1.w);
}

extern "C" void kernel_launch(void* const* d_in, const int* in_sizes, int n_in,
                              void* d_out, int out_size, void* d_ws, size_t ws_size,
                              hipStream_t stream) {
    const float* x  = (const float*)d_in[0];
    const float* cp = (const float*)d_in[1];
    const float* w1 = (const float*)d_in[2];
    const float* w2 = (const float*)d_in[3];
    _Float16* wsw = (_Float16*)d_ws;   // 1.31 MB

    prep_wsw<<<NSLOT / 256, 256, 0, stream>>>(cp, w1, w2, wsw);
    hipMemsetAsync(d_out, 0, (size_t)out_size * sizeof(float), stream);
    kan_mfma<<<512, 256, 0, stream>>>(x, wsw, (float*)d_out);
}

// Round 3
// 91.810 us; speedup vs baseline: 1.8269x; 1.2826x over previous
//
#include <hip/hip_runtime.h>

// KAN conv as densified GEMM: out[px,f] = sum_k Basis[px,k] * W[k,f]
//   px = (b,p,q) 8192, f = 64, K = 16 chunks x 640:
//   chunk kl in [0,576): spline (cl*144 + ij*16 + g), taps (1-fr)@idx, fr@idx+1
//   chunk kl in [576,640): silu at cl*16 + ij (ij<9), rest zero-pad (W rows 0)
// W pre-swizzled to MFMA 16x16x32 f16 B-fragment order. Basis built in LDS with
// self-clearing scatter (no per-chunk zero pass). 3-way K-split -> partial
// buffers (plain stores) + combine kernel. No atomics, no memset.

typedef _Float16 v8h __attribute__((ext_vector_type(8)));
typedef float    v4f __attribute__((ext_vector_type(4)));

#define NSLOT   655360            // 10240 * 64 f16
#define PARTOFF 1310720           // bytes: wsw size
#define NPART   524288            // floats per partial (8192*64)

// Wsw slot ((ks*4+nt)*64+lane)*8+j = W[k=ks*32+(lane>>4)*8+j][f=nt*16+(lane&15)]
__global__ __launch_bounds__(256) void prep_wsw(const float* __restrict__ cp,
                                                const float* __restrict__ w1,
                                                const float* __restrict__ w2,
                                                _Float16* __restrict__ wsw) {
    int tid  = blockIdx.x * 256 + threadIdx.x;
    int j    = tid & 7;
    int lane = (tid >> 3) & 63;
    int rest = tid >> 9;
    int nt   = rest & 3;
    int ks   = rest >> 2;
    int k    = ks * 32 + ((lane >> 4) << 3) + j;
    int f    = (nt << 4) + (lane & 15);
    int chunk = k / 640;
    int kl    = k - chunk * 640;
    float val = 0.f;
    if (kl < 576) {
        int c = (chunk << 2) + kl / 144;
        int r = kl % 144;                       // ij*16 + g
        val = w1[f * 576 + c * 9 + (r >> 4)] * cp[f * 9216 + c * 144 + r];
    } else {
        int i2 = kl - 576;
        int ij = i2 & 15;
        if (ij < 9) {
            int c = (chunk << 2) + (i2 >> 4);
            val = w2[f * 576 + c * 9 + ij];
        }
    }
    wsw[tid] = (_Float16)val;
}

// grid 768: kh = blk>>8 (chunk range {0-5,6-10,11-15}), rowid = blk&255 = (b,p).
// WG = 32 px (one image row). 4 waves split each chunk's 20 ksteps (5 each);
// each wave holds the full 32x64 fp32 accumulator; LDS reduce at the end.
__global__ __launch_bounds__(256) void kan_mfma(const float* __restrict__ x,
                                                const _Float16* __restrict__ wsw,
                                                float* __restrict__ part) {
    __shared__ __align__(16) char smem[41472];
    _Float16* sb  = (_Float16*)smem;       // [32][648] f16 basis (stride 648: 2-way max)
    float*    red = (float*)smem;          // [4][32][65] f32 reduce, aliases sb

    int blk   = blockIdx.x;
    int kh    = blk >> 8;
    int rowid = blk & 255;
    int b = rowid >> 5, p = rowid & 31;
    int t = threadIdx.x, wv = t >> 6, lane = t & 63;
    int m = lane & 15, kq = lane >> 4;

    const int chs[4] = {0, 6, 11, 16};
    int ch0 = chs[kh], ch1 = chs[kh + 1];

    // one-time zero of the whole basis region (keeps W==0 slots NaN-free too)
    v4f z4 = (v4f){0.f, 0.f, 0.f, 0.f};
    for (int i4 = t; i4 < 2592; i4 += 256) ((v4f*)sb)[i4] = z4;
    __syncthreads();

    v4f acc[2][4];
#pragma unroll
    for (int i = 0; i < 2; ++i)
#pragma unroll
        for (int n = 0; n < 4; ++n) acc[i][n] = z4;

    int prevIdx[5];
    const float* xb = x + (size_t)b * 65536;   // (b) base, rows of 32*64

    for (int gch = ch0; gch < ch1; ++gch) {
        int cbase = gch << 2;
        // ---- scatter: 32 px * 4 c * 9 ij = 1152 events, self-clearing ----
#pragma unroll
        for (int it = 0; it < 5; ++it) {
            int e = t + it * 256;
            if (e < 1152) {
                int px = e / 36;
                int r  = e - px * 36;
                int cl = r / 9;
                int ij = r - cl * 9;
                int di = ij / 3;
                int dj = ij - di * 3;
                int row = p + di - 1;
                int col = px + dj - 1;
                float v = 0.f;
                if ((unsigned)row < 32u && (unsigned)col < 32u)
                    v = xb[(row * 32 + col) * 64 + cbase + cl];
                float xc = fminf(fmaxf(v, -1.f), 1.f);
                float tt = (xc + 1.f) * 7.5f;
                int idx = (int)tt;
                if (idx > 14) idx = 14;
                float fr = tt - (float)idx;
                float sv = v * __builtin_amdgcn_rcpf(1.f + __expf(-v));
                _Float16* rowp = sb + px * 648 + cl * 144 + ij * 16;
                if (gch > ch0) {
                    int pi = prevIdx[it];
                    rowp[pi]     = (_Float16)0.f;
                    rowp[pi + 1] = (_Float16)0.f;
                }
                rowp[idx]     = (_Float16)(1.f - fr);
                rowp[idx + 1] = (_Float16)fr;
                sb[px * 648 + 576 + cl * 16 + ij] = (_Float16)sv;
                prevIdx[it] = idx;
            }
        }
        __syncthreads();
        // ---- MFMA: 20 ksteps, this wave takes 5 ----
        const _Float16* ap0 = sb + m * 648 + (wv * 5) * 32 + kq * 8;
        const v8h* bp = (const v8h*)wsw + ((size_t)gch * 20 + wv * 5) * 256 + lane;
#pragma unroll
        for (int s = 0; s < 5; ++s) {
            v8h a0 = *(const v8h*)(ap0 + s * 32);
            v8h a1 = *(const v8h*)(ap0 + s * 32 + 16 * 648);
            v8h b0 = bp[s * 256];
            v8h b1 = bp[s * 256 + 64];
            v8h b2 = bp[s * 256 + 128];
            v8h b3 = bp[s * 256 + 192];
            acc[0][0] = __builtin_amdgcn_mfma_f32_16x16x32_f16(a0, b0, acc[0][0], 0, 0, 0);
            acc[0][1] = __builtin_amdgcn_mfma_f32_16x16x32_f16(a0, b1, acc[0][1], 0, 0, 0);
            acc[0][2] = __builtin_amdgcn_mfma_f32_16x16x32_f16(a0, b2, acc[0][2], 0, 0, 0);
            acc[0][3] = __builtin_amdgcn_mfma_f32_16x16x32_f16(a0, b3, acc[0][3], 0, 0, 0);
            acc[1][0] = __builtin_amdgcn_mfma_f32_16x16x32_f16(a1, b0, acc[1][0], 0, 0, 0);
            acc[1][1] = __builtin_amdgcn_mfma_f32_16x16x32_f16(a1, b1, acc[1][1], 0, 0, 0);
            acc[1][2] = __builtin_amdgcn_mfma_f32_16x16x32_f16(a1, b2, acc[1][2], 0, 0, 0);
            acc[1][3] = __builtin_amdgcn_mfma_f32_16x16x32_f16(a1, b3, acc[1][3], 0, 0, 0);
        }
        __syncthreads();
    }

    // ---- 4-wave LDS reduction, then plain coalesced stores to partial ----
#pragma unroll
    for (int mt = 0; mt < 2; ++mt)
#pragma unroll
        for (int nt = 0; nt < 4; ++nt)
#pragma unroll
            for (int r = 0; r < 4; ++r)
                red[wv * 2080 + (mt * 16 + kq * 4 + r) * 65 + nt * 16 + m] = acc[mt][nt][r];
    __syncthreads();
    int f = t & 63, pxg = t >> 6;
    float* op = part + (size_t)kh * NPART + rowid * 2048 + f;
#pragma unroll
    for (int i = 0; i < 8; ++i) {
        int px = pxg * 8 + i;
        float s = red[px * 65 + f] + red[2080 + px * 65 + f]
                + red[4160 + px * 65 + f] + red[6240 + px * 65 + f];
        op[px * 64] = s;
    }
}

__global__ __launch_bounds__(256) void combine(const float* __restrict__ part,
                                               float* __restrict__ out) {
    int i = blockIdx.x * 256 + threadIdx.x;
    v4f a = ((const v4f*)part)[i];
    v4f b = ((const v4f*)(part + NPART))[i];
    v4f c = ((const v4f*)(part + 2 * NPART))[i];
    ((v4f*)out)[i] = a + b + c;
}

extern "C" void kernel_launch(void* const* d_in, const int* in_sizes, int n_in,
                              void* d_out, int out_size, void* d_ws, size_t ws_size,
                              hipStream_t stream) {
    const float* x  = (const float*)d_in[0];
    const float* cp = (const float*)d_in[1];
    const float* w1 = (const float*)d_in[2];
    const float* w2 = (const float*)d_in[3];
    _Float16* wsw = (_Float16*)d_ws;                       // 1.31 MB
    float*    prt = (float*)((char*)d_ws + PARTOFF);       // 3 x 2 MB partials

    prep_wsw<<<NSLOT / 256, 256, 0, stream>>>(cp, w1, w2, wsw);
    kan_mfma<<<768, 256, 0, stream>>>(x, wsw, prt);
    combine<<<512, 256, 0, stream>>>(prt, (float*)d_out);
}

// Round 4
// 89.539 us; speedup vs baseline: 1.8732x; 1.0254x over previous
//
#include <hip/hip_runtime.h>

// KAN conv as densified GEMM: out[px,f] = sum_k Basis[px,k] * W[k,f]
//   px = (b,p,q) 8192, f = 64, K = 16 chunks x 640:
//   chunk kl in [0,576): spline (cl*144 + ij*16 + g), taps (1-fr)@idx, fr@idx+1
//   chunk kl in [576,640): silu at cl*16 + ij (ij<9), rest zero-pad (W rows 0)
// W pre-swizzled to MFMA 16x16x32 f16 B-fragment order. Basis built in LDS with
// self-clearing scatter; per-thread event geometry hoisted out of the chunk
// loop; x values software-prefetched one chunk ahead so no global latency sits
// inside the barrier-serialized scatter window. 3-way K-split -> partials +
// combine kernel. No atomics, no memset.

typedef _Float16 v8h __attribute__((ext_vector_type(8)));
typedef float    v4f __attribute__((ext_vector_type(4)));

#define NSLOT   655360            // 10240 * 64 f16
#define PARTOFF 1310720           // bytes: wsw size
#define NPART   524288            // floats per partial (8192*64)

// Wsw slot ((ks*4+nt)*64+lane)*8+j = W[k=ks*32+(lane>>4)*8+j][f=nt*16+(lane&15)]
__global__ __launch_bounds__(256) void prep_wsw(const float* __restrict__ cp,
                                                const float* __restrict__ w1,
                                                const float* __restrict__ w2,
                                                _Float16* __restrict__ wsw) {
    int tid  = blockIdx.x * 256 + threadIdx.x;
    int j    = tid & 7;
    int lane = (tid >> 3) & 63;
    int rest = tid >> 9;
    int nt   = rest & 3;
    int ks   = rest >> 2;
    int k    = ks * 32 + ((lane >> 4) << 3) + j;
    int f    = (nt << 4) + (lane & 15);
    int chunk = k / 640;
    int kl    = k - chunk * 640;
    float val = 0.f;
    if (kl < 576) {
        int c = (chunk << 2) + kl / 144;
        int r = kl % 144;                       // ij*16 + g
        val = w1[f * 576 + c * 9 + (r >> 4)] * cp[f * 9216 + c * 144 + r];
    } else {
        int i2 = kl - 576;
        int ij = i2 & 15;
        if (ij < 9) {
            int c = (chunk << 2) + (i2 >> 4);
            val = w2[f * 576 + c * 9 + ij];
        }
    }
    wsw[tid] = (_Float16)val;
}

// grid 768: kh = blk>>8 (chunk range {0-5,6-10,11-15}), rowid = blk&255 = (b,p).
// WG = 32 px (one image row). 4 waves split each chunk's 20 ksteps (5 each);
// each wave holds the full 32x64 fp32 accumulator; LDS reduce at the end.
__global__ __launch_bounds__(256, 3) void kan_mfma(const float* __restrict__ x,
                                                   const _Float16* __restrict__ wsw,
                                                   float* __restrict__ part) {
    __shared__ __align__(16) char smem[41472];
    _Float16* sb  = (_Float16*)smem;       // [32][648] f16 basis (stride 648)
    float*    red = (float*)smem;          // [4][32][65] f32 reduce, aliases sb

    int blk   = blockIdx.x;
    int kh    = blk >> 8;
    int rowid = blk & 255;
    int b = rowid >> 5, p = rowid & 31;
    int t = threadIdx.x, wv = t >> 6, lane = t & 63;
    int m = lane & 15, kq = lane >> 4;

    const int chs[4] = {0, 6, 11, 16};
    int ch0 = chs[kh], ch1 = chs[kh + 1];

    // one-time zero of the whole basis region
    v4f z4 = (v4f){0.f, 0.f, 0.f, 0.f};
    for (int i4 = t; i4 < 2592; i4 += 256) ((v4f*)sb)[i4] = z4;

    // ---- hoist per-thread event geometry (chunk-invariant) ----
    const float* xb = x + (size_t)b * 65536;
    int  off0[5], sbb[5], sil[5];
    bool okv[5];
#pragma unroll
    for (int it = 0; it < 5; ++it) {
        int e  = t + it * 256;
        int ec = e < 1152 ? e : 0;           // dummy for inactive slots
        int px = ec / 36;
        int r  = ec - px * 36;
        int cl = r / 9;
        int ij = r - cl * 9;
        int di = ij / 3;
        int dj = ij - di * 3;
        int row = p + di - 1;
        int col = px + dj - 1;
        okv[it]  = ((unsigned)row < 32u) && ((unsigned)col < 32u) && (e < 1152);
        off0[it] = okv[it] ? ((row * 32 + col) * 64 + cl) : 0;
        sbb[it]  = px * 648 + cl * 144 + ij * 16;
        sil[it]  = px * 648 + 576 + cl * 16 + ij;
    }

    v4f acc[2][4];
#pragma unroll
    for (int i = 0; i < 2; ++i)
#pragma unroll
        for (int n = 0; n < 4; ++n) acc[i][n] = z4;

    // prologue prefetch for first chunk
    float vbuf[5];
#pragma unroll
    for (int it = 0; it < 5; ++it)
        vbuf[it] = okv[it] ? xb[off0[it] + ch0 * 4] : 0.f;

    int prevIdx[5];
    __syncthreads();   // basis zeroed

    for (int gch = ch0; gch < ch1; ++gch) {
        // ---- scatter: params from prefetched registers, short VALU chain ----
#pragma unroll
        for (int it = 0; it < 5; ++it) {
            if (t + it * 256 < 1152) {       // wave-uniform (boundary at t=128)
                float v  = vbuf[it];
                float xc = fminf(fmaxf(v, -1.f), 1.f);
                float tt = (xc + 1.f) * 7.5f;
                int idx  = (int)tt;
                if (idx > 14) idx = 14;
                float fr = tt - (float)idx;
                float sv = v * __builtin_amdgcn_rcpf(1.f + __expf(-v));
                _Float16* rowp = sb + sbb[it];
                if (gch > ch0) {
                    int pi = prevIdx[it];
                    rowp[pi]     = (_Float16)0.f;
                    rowp[pi + 1] = (_Float16)0.f;
                }
                rowp[idx]     = (_Float16)(1.f - fr);
                rowp[idx + 1] = (_Float16)fr;
                sb[sil[it]]   = (_Float16)sv;
                prevIdx[it] = idx;
            }
        }
        // ---- prefetch next chunk's x (latency overlaps barrier + MFMA) ----
        if (gch + 1 < ch1) {
#pragma unroll
            for (int it = 0; it < 5; ++it)
                vbuf[it] = okv[it] ? xb[off0[it] + (gch + 1) * 4] : 0.f;
        }
        __syncthreads();
        // ---- MFMA: 20 ksteps, this wave takes 5 ----
        const _Float16* ap0 = sb + m * 648 + (wv * 5) * 32 + kq * 8;
        const v8h* bp = (const v8h*)wsw + ((size_t)gch * 20 + wv * 5) * 256 + lane;
#pragma unroll
        for (int s = 0; s < 5; ++s) {
            v8h a0 = *(const v8h*)(ap0 + s * 32);
            v8h a1 = *(const v8h*)(ap0 + s * 32 + 16 * 648);
            v8h b0 = bp[s * 256];
            v8h b1 = bp[s * 256 + 64];
            v8h b2 = bp[s * 256 + 128];
            v8h b3 = bp[s * 256 + 192];
            acc[0][0] = __builtin_amdgcn_mfma_f32_16x16x32_f16(a0, b0, acc[0][0], 0, 0, 0);
            acc[0][1] = __builtin_amdgcn_mfma_f32_16x16x32_f16(a0, b1, acc[0][1], 0, 0, 0);
            acc[0][2] = __builtin_amdgcn_mfma_f32_16x16x32_f16(a0, b2, acc[0][2], 0, 0, 0);
            acc[0][3] = __builtin_amdgcn_mfma_f32_16x16x32_f16(a0, b3, acc[0][3], 0, 0, 0);
            acc[1][0] = __builtin_amdgcn_mfma_f32_16x16x32_f16(a1, b0, acc[1][0], 0, 0, 0);
            acc[1][1] = __builtin_amdgcn_mfma_f32_16x16x32_f16(a1, b1, acc[1][1], 0, 0, 0);
            acc[1][2] = __builtin_amdgcn_mfma_f32_16x16x32_f16(a1, b2, acc[1][2], 0, 0, 0);
            acc[1][3] = __builtin_amdgcn_mfma_f32_16x16x32_f16(a1, b3, acc[1][3], 0, 0, 0);
        }
        __syncthreads();
    }

    // ---- 4-wave LDS reduction, then plain coalesced stores to partial ----
#pragma unroll
    for (int mt = 0; mt < 2; ++mt)
#pragma unroll
        for (int nt = 0; nt < 4; ++nt)
#pragma unroll
            for (int r = 0; r < 4; ++r)
                red[wv * 2080 + (mt * 16 + kq * 4 + r) * 65 + nt * 16 + m] = acc[mt][nt][r];
    __syncthreads();
    int f = t & 63, pxg = t >> 6;
    float* op = part + (size_t)kh * NPART + rowid * 2048 + f;
#pragma unroll
    for (int i = 0; i < 8; ++i) {
        int px = pxg * 8 + i;
        float s = red[px * 65 + f] + red[2080 + px * 65 + f]
                + red[4160 + px * 65 + f] + red[6240 + px * 65 + f];
        op[px * 64] = s;
    }
}

__global__ __launch_bounds__(256) void combine(const float* __restrict__ part,
                                               float* __restrict__ out) {
    int i = blockIdx.x * 256 + threadIdx.x;
    v4f a = ((const v4f*)part)[i];
    v4f b = ((const v4f*)(part + NPART))[i];
    v4f c = ((const v4f*)(part + 2 * NPART))[i];
    ((v4f*)out)[i] = a + b + c;
}

extern "C" void kernel_launch(void* const* d_in, const int* in_sizes, int n_in,
                              void* d_out, int out_size, void* d_ws, size_t ws_size,
                              hipStream_t stream) {
    const float* x  = (const float*)d_in[0];
    const float* cp = (const float*)d_in[1];
    const float* w1 = (const float*)d_in[2];
    const float* w2 = (const float*)d_in[3];
    _Float16* wsw = (_Float16*)d_ws;                       // 1.31 MB
    float*    prt = (float*)((char*)d_ws + PARTOFF);       // 3 x 2 MB partials

    prep_wsw<<<NSLOT / 256, 256, 0, stream>>>(cp, w1, w2, wsw);
    kan_mfma<<<768, 256, 0, stream>>>(x, wsw, prt);
    combine<<<512, 256, 0, stream>>>(prt, (float*)d_out);
}